// Round 8
// baseline (469.152 us; speedup 1.0000x reference)
//
#include <hip/hip_runtime.h>
#include <hip/hip_bf16.h>
#include <stdint.h>

typedef __attribute__((ext_vector_type(4))) float f32x4;
typedef __attribute__((ext_vector_type(8))) short short8v;

typedef __attribute__((address_space(1))) void gvoid;
typedef __attribute__((address_space(3))) void lvoid;

#define GLD16(gp, lp) __builtin_amdgcn_global_load_lds((const gvoid*)(gp), (lvoid*)(lp), 16, 0, 0)

__device__ __forceinline__ unsigned short f2bf(float f) {
    union { float ff; unsigned uu; } a; a.ff = f;
    unsigned u = a.uu;
    u += 0x7FFFu + ((u >> 16) & 1u);   // RNE; inputs finite
    return (unsigned short)(u >> 16);
}

// ---- Ub[o][r] = bf16(U[o][r] * (S[r]+eps[r])), row-major [4096][4096] ----
__global__ __launch_bounds__(256) void prep_u_kernel(
    const float* __restrict__ U, const float* __restrict__ S,
    const float* __restrict__ eps, unsigned short* __restrict__ Ub) {
    long idx = ((long)blockIdx.x * 256 + threadIdx.x) * 8;
    int r = (int)(idx & 4095);
    f32x4 u0 = *(const f32x4*)(U + idx);
    f32x4 u1 = *(const f32x4*)(U + idx + 4);
    f32x4 s0 = *(const f32x4*)(S + r);
    f32x4 s1 = *(const f32x4*)(S + r + 4);
    f32x4 e0 = *(const f32x4*)(eps + r);
    f32x4 e1 = *(const f32x4*)(eps + r + 4);
    union { uint4 v; unsigned short s[8]; } o;
#pragma unroll
    for (int j = 0; j < 4; ++j) {
        o.s[j]     = f2bf(u0[j] * (s0[j] + e0[j]));
        o.s[j + 4] = f2bf(u1[j] * (s1[j] + e1[j]));
    }
    *(uint4*)(Ub + idx) = o.v;
}

// ---- generic fp32 -> bf16 convert, 8 elems/thread ----
__global__ __launch_bounds__(256) void cvt_bf16_kernel(
    const float* __restrict__ src, unsigned short* __restrict__ dst) {
    long idx = ((long)blockIdx.x * 256 + threadIdx.x) * 8;
    f32x4 v0 = *(const f32x4*)(src + idx);
    f32x4 v1 = *(const f32x4*)(src + idx + 4);
    union { uint4 v; unsigned short s[8]; } o;
#pragma unroll
    for (int j = 0; j < 4; ++j) {
        o.s[j]     = f2bf(v0[j]);
        o.s[j + 4] = f2bf(v1[j]);
    }
    *(uint4*)(dst + idx) = o.v;
}

// ---- VtT[k][r] = bf16(Vt[r][k]); 64x64 tiles, padded LDS (conflict-free) ----
__global__ __launch_bounds__(256) void transpose_cvt_kernel(
    const float* __restrict__ src, unsigned short* __restrict__ dst) {
    __shared__ float tile[64][65];
    int tx = threadIdx.x & 63;
    int tq = threadIdx.x >> 6;
    int r0 = blockIdx.y << 6;
    int k0 = blockIdx.x << 6;
#pragma unroll
    for (int i = 0; i < 16; ++i) {
        int row = (i << 2) + tq;
        tile[row][tx] = src[(long)(r0 + row) * 4096 + k0 + tx];
    }
    __syncthreads();
#pragma unroll
    for (int i = 0; i < 16; ++i) {
        int krow = (i << 2) + tq;
        dst[(long)(k0 + krow) * 4096 + r0 + tx] = f2bf(tile[tx][krow]);
    }
}

// =====================================================================
// 256x256-tile 4-phase (MERGED) NT GEMM. C = A * B^T (+bias), bf16 in.
// 512 thr = 8 waves (2M x 4N), wave tile 128x64, BK=64, dbuf LDS ring
// identical to round 3/6 ([256][32] chunks, XOR slot^=(row>>1)&3 both
// sides, 0 measured conflicts; same stage order, same VM4 ring).
//
// CHANGE vs round 6: phase-pairs merged. Per merged phase Q:
//   {12 ds_reads (A mh0+mh1 + B, one k-half) | stage 2 chunks} ->
//   barrier -> lgkmcnt(0) -> 32 MFMA -> (VM4 at Q2/Q4) -> barrier.
// 4 phases/iter, 8 barriers (was 16). Tests whether the ~620cy/phase
// fixed sync overhead (r6 vs r7: barrier count & read pipelining both
// null) amortizes with phase length.
// Ring legality (pairwise from r6): stages Q1:{A11,B11} Q2:{A00',B00'}
// Q3:{A01',B01'} Q4:{A10',B10'}; VM4@Q2 confirms Q1's chunks (read Q3),
// VM4@Q4 confirms Q2+Q3's (read next Q1/Q2); Q4's confirmed next VM4@Q2
// (read Q3) -- all >=1 phase margin. WAR: every chunk's last read
// completes before its wave's lgkm0 in phase p; re-stage issues after
// the p-end barrier. All 8 chunks checked.
// =====================================================================
#define MM(a, b, c) __builtin_amdgcn_mfma_f32_16x16x32_bf16(a, b, c, 0, 0, 0)

#define ACH(bf, kh) (As + ((bf) * 2 + (kh)) * 8192)
#define BCH(bf, kh) (Bs + ((bf) * 2 + (kh)) * 8192)

#define STAGE_A(bf, kh, koff) do { \
    const unsigned short* _s = A + gAr + (koff); \
    unsigned short* _d = ACH(bf, kh) + wave * 512; \
    GLD16(_s, _d); GLD16(_s + (long)128 * K, _d + 4096); } while (0)

#define STAGE_B(bf, kh, koff) do { \
    const unsigned short* _s = B + gBr + (koff); \
    unsigned short* _d = BCH(bf, kh) + wave * 512; \
    GLD16(_s, _d); GLD16(_s + (long)128 * K, _d + 4096); } while (0)

// A-frags, BOTH m-halves, one k-half: 8 x ds_read_b128
#define LOAD_A2(bf, ks) do { \
    const unsigned short* _p = ACH(bf, ks) + aBase; \
    _Pragma("unroll") \
    for (int _m = 0; _m < 4; ++_m) { \
        aR[0][_m] = *(const short8v*)(_p + _m * 512); \
        aR[1][_m] = *(const short8v*)(_p + _m * 512 + 2048); } } while (0)

// B-frags, one k-half: 4 x ds_read_b128
#define READ_B(bf, ks) do { \
    const unsigned short* _p = BCH(bf, ks) + bBase; \
    _Pragma("unroll") \
    for (int _n = 0; _n < 4; ++_n) bR[_n] = *(const short8v*)(_p + _n * 512); } while (0)

#define PH_SYNC do { \
    __builtin_amdgcn_s_barrier(); \
    asm volatile("s_waitcnt lgkmcnt(0)" ::: "memory"); } while (0)

// 32 MFMA: both m-halves x 4 n-frags, one k-half
#define MFMA32 do { \
    __builtin_amdgcn_s_setprio(1); \
    _Pragma("unroll") \
    for (int _h = 0; _h < 2; ++_h) \
    _Pragma("unroll") \
    for (int _m = 0; _m < 4; ++_m) { \
        acc[_h * 4 + _m][0] = MM(aR[_h][_m], bR[0], acc[_h * 4 + _m][0]); \
        acc[_h * 4 + _m][1] = MM(aR[_h][_m], bR[1], acc[_h * 4 + _m][1]); \
        acc[_h * 4 + _m][2] = MM(aR[_h][_m], bR[2], acc[_h * 4 + _m][2]); \
        acc[_h * 4 + _m][3] = MM(aR[_h][_m], bR[3], acc[_h * 4 + _m][3]); \
    } \
    __builtin_amdgcn_s_setprio(0); } while (0)

#define VM4 asm volatile("s_waitcnt vmcnt(4)" ::: "memory")
#define PH_END __builtin_amdgcn_s_barrier()

template<int OUT_BF16, int BIAS>
__global__ __launch_bounds__(512, 2) void gemm256_kernel(
    const unsigned short* __restrict__ A,   // [M][K] bf16 bits
    const unsigned short* __restrict__ B,   // [N][K] bf16 bits
    void* __restrict__ Cv, const float* __restrict__ bias,
    int M, int N, int K) {
    __shared__ unsigned short As[4 * 8192];   // 64 KB
    __shared__ unsigned short Bs[4 * 8192];   // 64 KB

    const int tid  = threadIdx.x;
    const int wave = tid >> 6;
    const int lane = tid & 63;
    const int fr   = lane & 15;
    const int fq   = lane >> 4;

    // XCD-aware bijective swizzle (nwg % 8 == 0 for all launches)
    const int nwg = gridDim.x;
    const int bid = blockIdx.x;
    const int cpx = nwg >> 3;
    const int wg  = (bid & 7) * cpx + (bid >> 3);
    const int ntn = N >> 8;
    const long m0 = (long)(wg / ntn) << 8;
    const long n0 = (long)(wg % ntn) << 8;

    const int wwr = wave >> 2;   // 0..1  (M half)
    const int wwc = wave & 3;    // 0..3  (N quarter)

    // Stage addressing (verified): chunk [256 rows][32 k] bf16, 1024
    // 16B slots; global src slot = (si&3) ^ ((row>>1)&3).
    const int  rS  = tid >> 2;                        // rows rS and rS+128
    const int  sS  = (tid & 3) ^ ((rS >> 1) & 3);
    const long gAr = (m0 + rS) * K + sS * 8;
    const long gBr = (n0 + rS) * K + sS * 8;

    // ds_read addressing (swizzled): elem = row*32 + ((fq ^ ((row>>1)&3))*8)
    const int swz   = (fq ^ ((fr >> 1) & 3)) * 8;
    const int aBase = (wwr * 128 + fr) * 32 + swz;
    const int bBase = (wwc * 64 + fr) * 32 + swz;

    f32x4  acc[8][4] = {};
    short8v aR[2][4], bR[4];

    // Prologue: stage (0,0),(0,1),(1,0); VM4 confirms (0,0),(0,1).
    STAGE_A(0, 0, 0);  STAGE_B(0, 0, 0);
    STAGE_A(0, 1, 32); STAGE_B(0, 1, 32);
    STAGE_A(1, 0, 64); STAGE_B(1, 0, 64);
    VM4;
    __builtin_amdgcn_s_barrier();

    const int nIter = K >> 7;   // 2 K-tiles (BK=64) per iteration
    for (int i = 0; i < nIter; ++i) {
        const int kt1off = 128 * i + 96;              // buf1.kh1 (in-bounds)
        int k3 = 128 * i + 128; if (k3 >= K) k3 -= K; // next buf0.kh0 (wrap: dead)
        int k5 = 128 * i + 160; if (k5 >= K) k5 -= K; // next buf0.kh1
        int k7 = 128 * i + 192; if (k7 >= K) k7 -= K; // next buf1.kh0

        // Q1: compute buf0.k0 (both mh); stage A11,B11
        LOAD_A2(0, 0); READ_B(0, 0); STAGE_A(1, 1, kt1off); STAGE_B(1, 1, kt1off);
        PH_SYNC; MFMA32; PH_END;
        // Q2: compute buf0.k1; stage next A00,B00; VM4 confirms A11,B11
        LOAD_A2(0, 1); READ_B(0, 1); STAGE_A(0, 0, k3); STAGE_B(0, 0, k3);
        PH_SYNC; MFMA32; VM4; PH_END;
        // Q3: compute buf1.k0; stage next A01,B01
        LOAD_A2(1, 0); READ_B(1, 0); STAGE_A(0, 1, k5); STAGE_B(0, 1, k5);
        PH_SYNC; MFMA32; PH_END;
        // Q4: compute buf1.k1; stage next A10,B10; VM4 confirms Q2+Q3 stages
        LOAD_A2(1, 1); READ_B(1, 1); STAGE_A(1, 0, k7); STAGE_B(1, 0, k7);
        PH_SYNC; MFMA32; VM4; PH_END;
    }

    // Epilogue: C/D layout col = lane&15, row = (lane>>4)*4 + j
#pragma unroll
    for (int nf = 0; nf < 4; ++nf) {
        const int col = (int)n0 + wwc * 64 + nf * 16 + fr;
        float bv = BIAS ? bias[col] : 0.0f;
#pragma unroll
        for (int mf = 0; mf < 8; ++mf) {
            f32x4 v = acc[mf][nf];
            long rowb = m0 + wwr * 128 + mf * 16 + fq * 4;
#pragma unroll
            for (int j = 0; j < 4; ++j) {
                float val = v[j] + bv;
                long off = (rowb + j) * N + col;
                if (OUT_BF16) ((unsigned short*)Cv)[off] = f2bf(val);
                else          ((float*)Cv)[off] = val;
            }
        }
    }
}

extern "C" void kernel_launch(void* const* d_in, const int* in_sizes, int n_in,
                              void* d_out, int out_size, void* d_ws, size_t ws_size,
                              hipStream_t stream) {
    const float* x    = (const float*)d_in[0];   // [4,2048,4096] = [8192][4096]
    const float* U    = (const float*)d_in[1];   // [4096][4096]
    const float* S    = (const float*)d_in[2];   // [4096]
    const float* Vt   = (const float*)d_in[3];   // [4096][4096]
    const float* eps  = (const float*)d_in[4];   // [4096]
    const float* bias = (const float*)d_in[5];   // [4096]
    float* out = (float*)d_out;                  // [8192][4096] fp32

    char* ws = (char*)d_ws;
    unsigned short* Ub  = (unsigned short*)(ws);                       // 32 MB
    unsigned short* VtT = (unsigned short*)(ws + (size_t)(32 << 20));  // 32 MB
    unsigned short* Wb  = (unsigned short*)(ws + (size_t)(64 << 20));  // 32 MB
    unsigned short* Xb  = (unsigned short*)(ws);  // 64 MB, reuses Ub+VtT after GEMM1

    // 1) Ub = bf16(U * (S+eps))            [o][r]
    prep_u_kernel<<<8192, 256, 0, stream>>>(U, S, eps, Ub);
    // 2) VtT = bf16(Vt^T)                  [k][r]
    transpose_cvt_kernel<<<dim3(64, 64), 256, 0, stream>>>(Vt, VtT);
    // 3) Wb[o][k] = Ub @ VtT^T             (NT, K=r)  -> 256 wg
    gemm256_kernel<1, 0><<<256, 512, 0, stream>>>(Ub, VtT, (void*)Wb, nullptr,
                                                  4096, 4096, 4096);
    // 4) Xb = bf16(x)                      [m][k]  (overwrites Ub/VtT — now dead)
    cvt_bf16_kernel<<<16384, 256, 0, stream>>>(x, Xb);
    // 5) out[m][o] = Xb @ Wb^T + bias      (NT, K=k)  -> 512 wg
    gemm256_kernel<0, 1><<<512, 512, 0, stream>>>(Xb, Wb, (void*)out, bias,
                                                  8192, 4096, 4096);
}